// Round 1
// baseline (608.427 us; speedup 1.0000x reference)
//
#include <hip/hip_runtime.h>
#include <stdint.h>
#include <stddef.h>

#define D0 4096
#define D1 1024
#define NOUT 1000
#define NB 64

// ---------------------------------------------------------------------------
// Spike pattern for uniform spike coding, N in [0,32] -> 32-bit cycle mask.
// Matches jnp: spacing = 32.f/N (fp32), spike at c iff fmod(c, spacing) < 1.
// ---------------------------------------------------------------------------
__device__ __forceinline__ uint32_t spike_pattern(int N) {
  if (N <= 0) return 0u;
  if (N >= 32) return 0xFFFFFFFFu;
  float spacing = 32.0f / (float)N;
  uint32_t m = 0;
  for (int c = 0; c < 32; ++c) {
    if (fmodf((float)c, spacing) < 1.0f) m |= (1u << c);
  }
  return m;
}

// ---------------------------------------------------------------------------
// Transpose w0 (4096x4096) -> w0T[j][o].  float4 on both global sides.
// block (8,32): tx=0..7 (float4 column group), ty=0..31 (row).
// tile[A][B] = w[o0+A][j0+B]; +1 pad keeps LDS conflicts <= 2-way (free).
// ---------------------------------------------------------------------------
__global__ void transpose_w0_k(const float* __restrict__ w, float* __restrict__ wt) {
  __shared__ float tile[32][33];
  int j0 = blockIdx.x * 32;
  int o0 = blockIdx.y * 32;
  int tx = threadIdx.x, ty = threadIdx.y;
  float4 v = *reinterpret_cast<const float4*>(&w[(size_t)(o0 + ty) * D0 + j0 + 4 * tx]);
  tile[ty][4 * tx + 0] = v.x;
  tile[ty][4 * tx + 1] = v.y;
  tile[ty][4 * tx + 2] = v.z;
  tile[ty][4 * tx + 3] = v.w;
  __syncthreads();
  float4 u;
  u.x = tile[4 * tx + 0][ty];
  u.y = tile[4 * tx + 1][ty];
  u.z = tile[4 * tx + 2][ty];
  u.w = tile[4 * tx + 3][ty];
  *reinterpret_cast<float4*>(&wt[(size_t)(j0 + ty) * D0 + o0 + 4 * tx]) = u;
}

// Transpose w2 (1000x1024) -> w2T[j][o], o padded to 1024 with zeros.
__global__ void transpose_w2_k(const float* __restrict__ w, float* __restrict__ wt) {
  __shared__ float tile[32][33];
  int j0 = blockIdx.x * 32;
  int o0 = blockIdx.y * 32;
  int tx = threadIdx.x, ty = threadIdx.y;
  int o = o0 + ty;
  float4 v = make_float4(0.f, 0.f, 0.f, 0.f);
  if (o < NOUT) v = *reinterpret_cast<const float4*>(&w[(size_t)o * D1 + j0 + 4 * tx]);
  tile[ty][4 * tx + 0] = v.x;
  tile[ty][4 * tx + 1] = v.y;
  tile[ty][4 * tx + 2] = v.z;
  tile[ty][4 * tx + 3] = v.w;
  __syncthreads();
  float4 u;
  u.x = tile[4 * tx + 0][ty];
  u.y = tile[4 * tx + 1][ty];
  u.z = tile[4 * tx + 2][ty];
  u.w = tile[4 * tx + 3][ty];
  *reinterpret_cast<float4*>(&wt[(size_t)(j0 + ty) * D1 + o0 + 4 * tx]) = u;
}

// ---------------------------------------------------------------------------
// N0(b,d) = round_half_even(x * 32)   (matches jnp.round in fp32)
// ---------------------------------------------------------------------------
__global__ void compute_N0_k(const float* __restrict__ x, int* __restrict__ N0) {
  int i = blockIdx.x * 256 + threadIdx.x;
  N0[i] = (int)rintf(x[i] * 32.0f);
}

// ---------------------------------------------------------------------------
// Per-batch counting sort of D inputs by key = Nsrc[b][idx[j]] (33 keys).
// perm[b][pos] = j, sorted ascending by key; starts[b][k] = bucket k begin.
// Order within a key is non-deterministic (atomics) — only perturbs fp64
// bucket-sum rounding at ~1e-16, irrelevant vs threshold margins.
// ---------------------------------------------------------------------------
template <int D>
__global__ void prep_sort_k(const int* __restrict__ Nsrc, const int* __restrict__ idx,
                            uint32_t* __restrict__ perm, int* __restrict__ starts) {
  __shared__ int keys[D];
  __shared__ int hist[33];
  __shared__ int base[34];
  __shared__ int cursor[33];
  int b = blockIdx.x;
  int tid = threadIdx.x;
  if (tid < 33) hist[tid] = 0;
  __syncthreads();
  for (int j = tid; j < D; j += 256) {
    int k = Nsrc[b * D + idx[j]];
    keys[j] = k;
    atomicAdd(&hist[k], 1);
  }
  __syncthreads();
  if (tid == 0) {
    int s = 0;
    for (int k = 0; k < 33; ++k) { base[k] = s; cursor[k] = s; s += hist[k]; }
    base[33] = s;
  }
  __syncthreads();
  if (tid < 34) starts[b * 34 + tid] = base[tid];
  for (int j = tid; j < D; j += 256) {
    int k = keys[j];
    int pos = atomicAdd(&cursor[k], 1);
    perm[b * D + pos] = (uint32_t)j;
  }
}

// ---------------------------------------------------------------------------
// LIF core via bucket decomposition, fp64-exact.
// Grid (gridDim.x, NB, 1); each block serially processes TILES o-tiles:
//   o_tile = blockIdx.x + gridDim.x * zt.
// For D0: gridDim.x = 8 -> XCD = linear_block_id % 8 = blockIdx.x, so ALL 64
// resident blocks of an XCD work the SAME 4 MB w0T column slice at a time
// (fits the 4 MB per-XCD L2), then move together to the second slice.
// Previous grid (8,NB,2) kept both slices concurrently resident (8 MB working
// set -> L2 thrash, 1 GB L3 refetch, latency-bound at 31% VALUBusy).
// 16-wide unrolled gather body: 16 loads in flight/wave x 8 waves/CU = 128,
// comfortably above the ~55 needed to cover L2-hit latency at the per-CU
// L2 bandwidth share.
// Segment bounds go through readfirstlane so trip counts / perm addressing
// are provably wave-uniform (scalar loads, scalar branches).
// fp64 lane-accumulator assignment (a[(i-s)%4]) preserved in all paths;
// only the sub-8 tail grouping changed (1e-16-level reorder, harmless —
// within-key order is already nondeterministic from prep_sort atomics).
// ---------------------------------------------------------------------------
template <int D, int OSTRIDE, int TILES>
__launch_bounds__(256, 2)
__global__ void lif_core_k(const float* __restrict__ wt, const uint32_t* __restrict__ perm,
                           const int* __restrict__ starts, const float* __restrict__ thr_p,
                           int* __restrict__ cnt_out) {
  __shared__ uint32_t pat[33];
  int tid = threadIdx.x;
  int b = blockIdx.y;
  if (tid < 33) pat[tid] = spike_pattern(tid);
  __syncthreads();

  const uint32_t* permb = perm + (size_t)b * D;
  const int* st = starts + b * 34;
  double th = (double)thr_p[0];

  for (int zt = 0; zt < TILES; ++zt) {
    int o = (blockIdx.x + gridDim.x * zt) * 256 + tid;

    double contrib[32];
#pragma unroll
    for (int t = 0; t < 32; ++t) contrib[t] = 0.0;

    for (int k = 1; k <= 32; ++k) {   // k=0: empty pattern, skip its segment
      int s = __builtin_amdgcn_readfirstlane(st[k]);
      int e = __builtin_amdgcn_readfirstlane(st[k + 1]);
      if (s == e) continue;           // scalar branch
      double a0 = 0.0, a1 = 0.0, a2 = 0.0, a3 = 0.0;
      int i = s;
      for (; i + 16 <= e; i += 16) {
        uint32_t j[16];
        float f[16];
#pragma unroll
        for (int u = 0; u < 16; ++u) j[u] = permb[i + u];
#pragma unroll
        for (int u = 0; u < 16; ++u) f[u] = wt[(size_t)j[u] * OSTRIDE + o];
#pragma unroll
        for (int u = 0; u < 16; u += 4) {
          a0 += (double)f[u + 0];
          a1 += (double)f[u + 1];
          a2 += (double)f[u + 2];
          a3 += (double)f[u + 3];
        }
      }
      for (; i + 4 <= e; i += 4) {
        uint32_t j0 = permb[i + 0], j1 = permb[i + 1], j2 = permb[i + 2], j3 = permb[i + 3];
        a0 += (double)wt[(size_t)j0 * OSTRIDE + o];
        a1 += (double)wt[(size_t)j1 * OSTRIDE + o];
        a2 += (double)wt[(size_t)j2 * OSTRIDE + o];
        a3 += (double)wt[(size_t)j3 * OSTRIDE + o];
      }
      for (; i < e; ++i)
        a0 += (double)wt[(size_t)permb[i] * OSTRIDE + o];
      double acc = (a0 + a1) + (a2 + a3);
      uint32_t m = pat[k];
#pragma unroll
      for (int t = 0; t < 32; ++t)
        contrib[t] += ((m >> t) & 1u) ? acc : 0.0;
    }

    double memb = 0.0;
    int cnt = 0;
#pragma unroll
    for (int t = 0; t < 32; ++t) {
      memb += contrib[t];
      if (memb > th) { memb -= th; ++cnt; }  // strict: threshold < memb
    }
    cnt_out[(size_t)b * OSTRIDE + o] = cnt;
  }
}

// ---------------------------------------------------------------------------
// avg_pool2d on exact spike counts + re-encode: N1 = round_half_even(count4/4)
// ---------------------------------------------------------------------------
__global__ void pool_encode_k(const int* __restrict__ k0, const int* __restrict__ idx1,
                              int* __restrict__ N1) {
  int i = blockIdx.x * 256 + threadIdx.x;  // 64*1024
  int b = i >> 10;
  int q2 = i & 1023;
  int c = q2 >> 4;
  int h2 = (q2 >> 2) & 3;
  int w2 = q2 & 3;
  int cnt = 0;
#pragma unroll
  for (int dh = 0; dh < 2; ++dh)
#pragma unroll
    for (int dw = 0; dw < 2; ++dw) {
      int q = c * 64 + (2 * h2 + dh) * 8 + (2 * w2 + dw);
      cnt += k0[b * D0 + idx1[q]];
    }
  N1[i] = (int)rintf((float)cnt * 0.25f);
}

__global__ void write_out_k(const int* __restrict__ cnt2, const int* __restrict__ idx_out,
                            float* __restrict__ out) {
  int i = blockIdx.x * 256 + threadIdx.x;
  if (i >= NB * NOUT) return;
  int b = i / NOUT;
  int r = i - b * NOUT;
  out[i] = (float)cnt2[b * D1 + idx_out[r]];
}

// ---------------------------------------------------------------------------
extern "C" void kernel_launch(void* const* d_in, const int* in_sizes, int n_in,
                              void* d_out, int out_size, void* d_ws, size_t ws_size,
                              hipStream_t stream) {
  const float* x      = (const float*)d_in[0];
  const float* w0     = (const float*)d_in[1];
  const float* t0     = (const float*)d_in[2];
  const float* w2     = (const float*)d_in[3];
  const float* t2     = (const float*)d_in[4];
  const int*   idx0   = (const int*)d_in[5];
  const int*   idx1   = (const int*)d_in[6];
  const int*   idx2   = (const int*)d_in[7];
  const int*   idx_out= (const int*)d_in[8];
  float* out = (float*)d_out;

  char* ws = (char*)d_ws;
  float*    w0T    = (float*)ws;    ws += (size_t)D0 * D0 * 4;   // 64 MB
  float*    w2T    = (float*)ws;    ws += (size_t)D1 * D1 * 4;   // 4 MB
  uint32_t* perm0  = (uint32_t*)ws; ws += (size_t)NB * D0 * 4;
  uint32_t* perm2  = (uint32_t*)ws; ws += (size_t)NB * D1 * 4;
  int*      N0     = (int*)ws;      ws += (size_t)NB * D0 * 4;
  int*      N1     = (int*)ws;      ws += (size_t)NB * D1 * 4;
  int*      k0     = (int*)ws;      ws += (size_t)NB * D0 * 4;
  int*      cnt2   = (int*)ws;      ws += (size_t)NB * D1 * 4;
  int*      starts0= (int*)ws;      ws += (size_t)NB * 34 * 4;
  int*      starts2= (int*)ws;      ws += (size_t)NB * 34 * 4;

  transpose_w0_k<<<dim3(D0 / 32, D0 / 32), dim3(8, 32), 0, stream>>>(w0, w0T);
  transpose_w2_k<<<dim3(D1 / 32, D1 / 32), dim3(8, 32), 0, stream>>>(w2, w2T);
  compute_N0_k<<<NB * D0 / 256, 256, 0, stream>>>(x, N0);
  prep_sort_k<D0><<<NB, 256, 0, stream>>>(N0, idx0, perm0, starts0);
  // 512 blocks (2/CU): per XCD, one 4 MB slice in flight at a time (L2-fit),
  // second slice processed after the first via the in-kernel zt loop.
  lif_core_k<D0, D0, 2><<<dim3(8, NB, 1), 256, 0, stream>>>(w0T, perm0, starts0, t0, k0);
  pool_encode_k<<<NB * D1 / 256, 256, 0, stream>>>(k0, idx1, N1);
  prep_sort_k<D1><<<NB, 256, 0, stream>>>(N1, idx2, perm2, starts2);
  lif_core_k<D1, D1, 1><<<dim3(D1 / 256, NB, 1), 256, 0, stream>>>(w2T, perm2, starts2, t2, cnt2);
  write_out_k<<<(NB * NOUT + 255) / 256, 256, 0, stream>>>(cnt2, idx_out, out);
}